// Round 15
// baseline (190.340 us; speedup 1.0000x reference)
//
#include <hip/hip_runtime.h>
#include <math.h>

#define IN_C 128
#define OUT_C 64
#define NEG_SLOPE 0.2f
#define GAT_EPS 1e-16f

// Single-pass fine binning with LDS aggregation (R5 structure, 7x passed).
// R11 WIN: int2-packed CSR (ds_read_b64). R14 WIN: nodeB 256->512 threads
// (nodeB 54.3->52.2us, occ 50->55%). R15 delta (same lever, one notch):
// NBT 512->1024 (16 waves/block): each wave owns 4 nodes (nl+=16), hist/CSR
// loops ~1 iteration at cnt~1024, residency can reach the 32-wave cap at
// 2 blocks/CU. Per-node lane layout, 4-deep gather, FP order unchanged.
// Ledger: R6 -36 (bin geometry), R8 -42 (nt stores; reg-staging+8-deep),
// R12 -10 (8-deep unbundled), R9 divergence = transient (R10 clean).
// Fine bucket: 64 dst nodes, cap 1536 (mean 1024, +16 sigma).
// Pack: (dst&63)<<20 | src  (needs N <= 2^20).
#define FSH 6
#define FN 64
#define CAPB 1536
#define PACKS 20
#define CHUNK 4096
#define BINT 1024
#define NBT 1024       // nodeB threads (16 waves)
#define NBW (NBT / 64) // nodeB waves per block
#define NFBA 1568      // allocated fine buckets
#define CSTR 4         // cursor stride in ints (16B) - split line serialization

typedef unsigned int uint;
typedef unsigned short ushort;
typedef __attribute__((ext_vector_type(8))) short bf16x8;
typedef __attribute__((ext_vector_type(4))) float f32x4;

__device__ __forceinline__ ushort f2bf(float f) {
    uint u = __float_as_uint(f);
    return (ushort)((u + 0x7fffu + ((u >> 16) & 1u)) >> 16);   // RNE
}

// MFMA gemm: h = bf16(x) @ bf16(W), h stored bf16; s_src/s_dst fp32 epilogue.
// 64 rows/block, 4 waves x (16 rows x 64 cols), K=128 = 4 x mfma_16x16x32_bf16.
// Also zeroes the bin cursors (first blocks) to save a launch.
__global__ __launch_bounds__(256) void gemm_kernel(
    const float* __restrict__ x, const float* __restrict__ W,
    const float* __restrict__ a_src, const float* __restrict__ a_dst,
    ushort* __restrict__ h16, float* __restrict__ s_src, float* __restrict__ s_dst,
    int N, int* __restrict__ zero_ptr, int zero_n)
{
    __shared__ __align__(16) ushort xs[64 * 128];   // [row][kq swizzled] 16B slots
    __shared__ __align__(16) ushort Wl[128 * 64];   // [kc][ct][lane][j]
    const int t = threadIdx.x;

    // fold cursor zeroing into the gemm launch
    {
        int zi = blockIdx.x * 256 + t;
        if (zi < zero_n) zero_ptr[zi] = 0;
    }

    // stage W: coalesced read, scattered bf16 LDS write
    #pragma unroll
    for (int q = 0; q < 8; q++) {
        float4 wv = ((const float4*)W)[t * 8 + q];
        #pragma unroll
        for (int e = 0; e < 4; e++) {
            int L = t * 32 + q * 4 + e;
            int k = L >> 6, col = L & 63;
            int kc = k >> 5, kg = (k >> 3) & 3, j = k & 7;
            int ct = col >> 4, c16 = col & 15;
            float v = (e == 0) ? wv.x : (e == 1) ? wv.y : (e == 2) ? wv.z : wv.w;
            Wl[(((kc * 4 + ct) * 4 + kg) * 16 + c16) * 8 + j] = f2bf(v);
        }
    }
    // stage x: thread handles row t>>2, k-range (t&3)*32..+31 (coalesced)
    const int row0 = blockIdx.x * 64;
    {
        int row_l = t >> 2;
        int grow = row0 + row_l;
        #pragma unroll
        for (int qq = 0; qq < 4; qq++) {
            int kq = (t & 3) * 4 + qq;           // 16B slot index along k
            float4 v0 = make_float4(0.f, 0.f, 0.f, 0.f);
            float4 v1 = v0;
            if (grow < N) {
                const float4* xp = (const float4*)(x + (size_t)grow * IN_C + kq * 8);
                v0 = xp[0]; v1 = xp[1];
            }
            uint4 pk;
            pk.x = (uint)f2bf(v0.x) | ((uint)f2bf(v0.y) << 16);
            pk.y = (uint)f2bf(v0.z) | ((uint)f2bf(v0.w) << 16);
            pk.z = (uint)f2bf(v1.x) | ((uint)f2bf(v1.y) << 16);
            pk.w = (uint)f2bf(v1.z) | ((uint)f2bf(v1.w) << 16);
            int slot = row_l * 16 + (kq ^ (row_l & 7));
            *(uint4*)&xs[slot * 8] = pk;
        }
    }
    __syncthreads();

    const int wv_ = t >> 6;       // wave id: rows wv_*16..+15
    const int l = t & 63;
    const int c16 = l & 15;
    const int quad = l >> 4;
    const int row_a = wv_ * 16 + c16;     // A-row this lane loads

    f32x4 acc[4] = {{0.f, 0.f, 0.f, 0.f}, {0.f, 0.f, 0.f, 0.f},
                    {0.f, 0.f, 0.f, 0.f}, {0.f, 0.f, 0.f, 0.f}};

    #pragma unroll
    for (int kc = 0; kc < 4; kc++) {
        int kq = kc * 4 + quad;
        bf16x8 a = *(const bf16x8*)&xs[(row_a * 16 + (kq ^ (row_a & 7))) * 8];
        #pragma unroll
        for (int ct = 0; ct < 4; ct++) {
            bf16x8 b = *(const bf16x8*)&Wl[(((kc * 4 + ct) * 4 + quad) * 16 + c16) * 8];
            acc[ct] = __builtin_amdgcn_mfma_f32_16x16x32_bf16(a, b, acc[ct], 0, 0, 0);
        }
    }

    // epilogue: C/D layout col = ct*16 + c16, row = wv_*16 + quad*4 + reg
    float as4[4], ad4[4];
    #pragma unroll
    for (int ct = 0; ct < 4; ct++) {
        as4[ct] = a_src[ct * 16 + c16];
        ad4[ct] = a_dst[ct * 16 + c16];
    }
    #pragma unroll
    for (int reg = 0; reg < 4; reg++) {
        int row = row0 + wv_ * 16 + quad * 4 + reg;
        float ps = acc[0][reg] * as4[0] + acc[1][reg] * as4[1]
                 + acc[2][reg] * as4[2] + acc[3][reg] * as4[3];
        float pd = acc[0][reg] * ad4[0] + acc[1][reg] * ad4[1]
                 + acc[2][reg] * ad4[2] + acc[3][reg] * ad4[3];
        ps += __shfl_xor(ps, 1);  pd += __shfl_xor(pd, 1);
        ps += __shfl_xor(ps, 2);  pd += __shfl_xor(pd, 2);
        ps += __shfl_xor(ps, 4);  pd += __shfl_xor(pd, 4);
        ps += __shfl_xor(ps, 8);  pd += __shfl_xor(pd, 8);
        if (row < N) {
            #pragma unroll
            for (int ct = 0; ct < 4; ct++)
                h16[(size_t)row * OUT_C + ct * 16 + c16] = f2bf(acc[ct][reg]);
            if (c16 == 0) { s_src[row] = ps; s_dst[row] = pd; }
        }
    }
}

// Binning: 1024 threads, 4 edges/thread. Pass 1 histograms + stages packed
// records in LDS; reservation = <=2 independent global atomics/thread;
// pass 2 scatters from LDS with LDS fetch-add (no global reads).
__global__ __launch_bounds__(1024) void bin3_kernel(
    const int* __restrict__ src, const int* __restrict__ dst,
    int* __restrict__ ccur, int* __restrict__ ebufB, int E)
{
    __shared__ int    hist[NFBA];    // per-block bucket counts -> base cursors
    __shared__ int    bcur[NFBA];    // reserved global base -> running cursor
    __shared__ int    rbuf[CHUNK];   // packed records
    __shared__ ushort rfb[CHUNK];    // bucket id per record
    const int t = threadIdx.x;
    const int e0 = blockIdx.x * CHUNK;
    int tot = E - e0; if (tot > CHUNK) tot = CHUNK;

    for (int i = t; i < NFBA; i += BINT) hist[i] = 0;
    __syncthreads();

    // pass 1: vectorized read, LDS hist + stage packed record
    const int i0 = t * 4;
    if (i0 < tot) {
        if (i0 + 3 < tot) {
            int4 d4 = *(const int4*)(dst + e0 + i0);
            int4 s4 = *(const int4*)(src + e0 + i0);
            int dd_[4] = {d4.x, d4.y, d4.z, d4.w};
            int ss_[4] = {s4.x, s4.y, s4.z, s4.w};
            #pragma unroll
            for (int k = 0; k < 4; k++) {
                int fb = dd_[k] >> FSH;
                atomicAdd(&hist[fb], 1);
                rbuf[i0 + k] = ((dd_[k] & (FN - 1)) << PACKS) | ss_[k];
                rfb[i0 + k] = (ushort)fb;
            }
        } else {
            for (int k = 0; k < 4 && i0 + k < tot; k++) {
                int dd = dst[e0 + i0 + k], ss = src[e0 + i0 + k];
                int fb = dd >> FSH;
                atomicAdd(&hist[fb], 1);
                rbuf[i0 + k] = ((dd & (FN - 1)) << PACKS) | ss;
                rfb[i0 + k] = (ushort)fb;
            }
        }
    }
    __syncthreads();

    // reservation: one independent global atomic per touched bucket
    for (int fb = t; fb < NFBA; fb += BINT) {
        int v = hist[fb];
        bcur[fb] = (v > 0) ? atomicAdd(&ccur[fb * CSTR], v) : 0;
    }
    __syncthreads();

    // pass 2: LDS-only re-read, scatter via LDS fetch-add
    if (i0 < tot) {
        #pragma unroll
        for (int k = 0; k < 4; k++) {
            if (i0 + k < tot) {
                int fb = rfb[i0 + k];
                int pos = atomicAdd(&bcur[fb], 1);
                if (pos < CAPB)
                    ebufB[(size_t)fb * CAPB + pos] = rbuf[i0 + k];
            }
        }
    }
}

// One block per fine bucket (64 dst nodes), 1024 threads = 16 waves: local
// hist/scan/scatter -> per-node CSR in LDS (packed int2), then 16 waves
// process nodes (nl += 16, 4 nodes/wave); lane = 2 bf16 channels, half-waves
// split edges, x4 unrolled gather. Per-node FP summation order unchanged.
__global__ __launch_bounds__(NBT) void nodeB_kernel(
    const int* __restrict__ ccurB, const int* __restrict__ ebufB,
    const float* __restrict__ s_src, const float* __restrict__ s_dst,
    const ushort* __restrict__ h16, const float* __restrict__ bias,
    float* __restrict__ out, int N)
{
    __shared__ __align__(8) int2 csr[CAPB];   // .x = src node, .y = exp bits
    __shared__ int lhist[FN], lofs[FN + 1], lcur[FN];

    const int b = blockIdx.x;
    const int t = threadIdx.x;
    const int node0 = b << FSH;
    const int nn = min(FN, N - node0);
    int cnt = ccurB[b * CSTR]; if (cnt > CAPB) cnt = CAPB;
    const int base = b * CAPB;

    if (t < FN) lhist[t] = 0;
    __syncthreads();
    for (int i = t; i < cnt; i += NBT)
        atomicAdd(&lhist[(ebufB[base + i] >> PACKS) & (FN - 1)], 1);
    __syncthreads();
    if (t < FN) {
        int v = lhist[t];
        int incl = v;
        #pragma unroll
        for (int off = 1; off < FN; off <<= 1) {
            int u = __shfl_up(incl, off);
            if (t >= off) incl += u;
        }
        lofs[t + 1] = incl;
        lcur[t] = incl - v;
        if (t == 0) lofs[0] = 0;
    }
    __syncthreads();
    for (int i = t; i < cnt; i += NBT) {      // re-read ebufB: L2-hit
        int pk = ebufB[base + i];
        int ld = (pk >> PACKS) & (FN - 1);
        int sj = pk & ((1 << PACKS) - 1);
        int q = atomicAdd(&lcur[ld], 1);
        float lg = s_src[sj] + s_dst[node0 + ld];
        lg = (lg > 0.f) ? lg : NEG_SLOPE * lg;
        csr[q] = make_int2(sj, __float_as_int(__expf(lg)));
    }
    __syncthreads();

    const int w = t >> 6;         // wave id 0..15
    const int l = t & 63;
    const int h2 = l >> 5;        // which edge of the half-wave pair
    const int lp = l & 31;        // channel pair index
    const float b0 = bias[2 * lp], b1 = bias[2 * lp + 1];

    for (int nl = w; nl < nn; nl += NBW) {
        const int node = node0 + nl;
        const int jb = lofs[nl], je = lofs[nl + 1];
        float acc0 = 0.f, acc1 = 0.f, ds = 0.f;
        int j = jb + h2;
        for (; j + 6 < je; j += 8) {          // 4 edges per half-wave in flight
            int2 c0 = csr[j],     c1 = csr[j + 2];
            int2 c2 = csr[j + 4], c3 = csr[j + 6];
            float e0 = __int_as_float(c0.y), e1 = __int_as_float(c1.y);
            float e2 = __int_as_float(c2.y), e3 = __int_as_float(c3.y);
            uint u0 = *(const uint*)&h16[(size_t)c0.x * OUT_C + 2 * lp];
            uint u1 = *(const uint*)&h16[(size_t)c1.x * OUT_C + 2 * lp];
            uint u2 = *(const uint*)&h16[(size_t)c2.x * OUT_C + 2 * lp];
            uint u3 = *(const uint*)&h16[(size_t)c3.x * OUT_C + 2 * lp];
            ds += (e0 + e1) + (e2 + e3);
            acc0 += e0 * __uint_as_float(u0 << 16) + e1 * __uint_as_float(u1 << 16)
                  + e2 * __uint_as_float(u2 << 16) + e3 * __uint_as_float(u3 << 16);
            acc1 += e0 * __uint_as_float(u0 & 0xffff0000u) + e1 * __uint_as_float(u1 & 0xffff0000u)
                  + e2 * __uint_as_float(u2 & 0xffff0000u) + e3 * __uint_as_float(u3 & 0xffff0000u);
        }
        for (; j < je; j += 2) {
            int2 c = csr[j];
            float e = __int_as_float(c.y);
            uint u = *(const uint*)&h16[(size_t)c.x * OUT_C + 2 * lp];
            ds += e;
            acc0 += e * __uint_as_float(u << 16);
            acc1 += e * __uint_as_float(u & 0xffff0000u);
        }
        acc0 += __shfl_xor(acc0, 32);
        acc1 += __shfl_xor(acc1, 32);
        ds   += __shfl_xor(ds, 32);

        float ls = s_src[node] + s_dst[node];
        ls = (ls > 0.f) ? ls : NEG_SLOPE * ls;
        float es = __expf(ls);
        uint us = *(const uint*)&h16[(size_t)node * OUT_C + 2 * lp];
        acc0 += es * __uint_as_float(us << 16);
        acc1 += es * __uint_as_float(us & 0xffff0000u);
        ds += es;

        float inv = 1.f / (ds + GAT_EPS);
        float v0 = acc0 * inv + b0;
        float v1 = acc1 * inv + b1;
        v0 = (v0 > 0.f) ? v0 : (__expf(v0) - 1.f);
        v1 = (v1 > 0.f) ? v1 : (__expf(v1) - 1.f);
        if (l < 32) *(float2*)&out[(size_t)node * OUT_C + 2 * lp] = make_float2(v0, v1);
    }
}

extern "C" void kernel_launch(void* const* d_in, const int* in_sizes, int n_in,
                              void* d_out, int out_size, void* d_ws, size_t ws_size,
                              hipStream_t stream)
{
    const float* x     = (const float*)d_in[0];
    const int*   ei    = (const int*)d_in[1];
    const float* W     = (const float*)d_in[2];
    const float* a_src = (const float*)d_in[3];
    const float* a_dst = (const float*)d_in[4];
    const float* b     = (const float*)d_in[5];
    float* out = (float*)d_out;

    const int N = in_sizes[0] / IN_C;
    const int E = in_sizes[1] / 2;
    const int NFB = (N + FN - 1) >> FSH;           // fine buckets (1563)
    const int GB = (N + 63) / 64;
    const int GBIN = (E + CHUNK - 1) / CHUNK;
    const int* src = ei;
    const int* dst = ei + E;

    // ws: h16[N*64] us | s_src[N] f | s_dst[N] f | ccur[NFBA*CSTR] | ebufB[NFBA*CAPB]
    ushort* h16    = (ushort*)d_ws;
    float* s_src_p = (float*)(h16 + (size_t)N * OUT_C);
    float* s_dst_p = s_src_p + N;
    int*   ccur    = (int*)(s_dst_p + N);
    int*   ebufB   = ccur + NFBA * CSTR;

    gemm_kernel<<<GB, 256, 0, stream>>>(x, W, a_src, a_dst, h16, s_src_p, s_dst_p,
                                        N, ccur, NFBA * CSTR);
    bin3_kernel<<<GBIN, BINT, 0, stream>>>(src, dst, ccur, ebufB, E);
    nodeB_kernel<<<NFB, NBT, 0, stream>>>(ccur, ebufB, s_src_p, s_dst_p, h16, b, out, N);
}

// Round 16
// 186.634 us; speedup vs baseline: 1.0199x; 1.0199x over previous
//
#include <hip/hip_runtime.h>
#include <math.h>

#define IN_C 128
#define OUT_C 64
#define NEG_SLOPE 0.2f
#define GAT_EPS 1e-16f

// FINAL (session-best, R14): single-pass fine binning with LDS aggregation,
// MFMA gemm, 8-wave nodeB with int2-packed CSR. 188.3us verified.
// Wins: R5 bin3 structure; R11 int2 CSR (ds_read_b64); R14 NBT 256->512
// (occ 50->55%, nodeB 54.3->52.2us).
// Confirmed-negative (all reverted): global per-edge atomics (+186us),
// nt stores on re-read buffers (+28), nodeB reg-staging (+9), 8-deep gather
// unroll (+6: half the nodes fall to cleanup at degree~Poisson(16)+1),
// NBT=1024 (+3: occ capped ~58%, FETCH +3MB, 16-wave barriers),
// bin CHUNK=2048 (+36), quarter-wave channel split (~+35).
// R9 divergence = transient (unreproducible; R10/R13 re-verified clean).
// Fine bucket: 64 dst nodes, cap 1536 (mean 1024, +16 sigma).
// Pack: (dst&63)<<20 | src  (needs N <= 2^20).
#define FSH 6
#define FN 64
#define CAPB 1536
#define PACKS 20
#define CHUNK 4096
#define BINT 1024
#define NBT 512        // nodeB threads (8 waves) - measured local optimum
#define NFBA 1568      // allocated fine buckets
#define CSTR 4         // cursor stride in ints (16B) - split line serialization

typedef unsigned int uint;
typedef unsigned short ushort;
typedef __attribute__((ext_vector_type(8))) short bf16x8;
typedef __attribute__((ext_vector_type(4))) float f32x4;

__device__ __forceinline__ ushort f2bf(float f) {
    uint u = __float_as_uint(f);
    return (ushort)((u + 0x7fffu + ((u >> 16) & 1u)) >> 16);   // RNE
}

// MFMA gemm: h = bf16(x) @ bf16(W), h stored bf16; s_src/s_dst fp32 epilogue.
// 64 rows/block, 4 waves x (16 rows x 64 cols), K=128 = 4 x mfma_16x16x32_bf16.
// Also zeroes the bin cursors (first blocks) to save a launch.
__global__ __launch_bounds__(256) void gemm_kernel(
    const float* __restrict__ x, const float* __restrict__ W,
    const float* __restrict__ a_src, const float* __restrict__ a_dst,
    ushort* __restrict__ h16, float* __restrict__ s_src, float* __restrict__ s_dst,
    int N, int* __restrict__ zero_ptr, int zero_n)
{
    __shared__ __align__(16) ushort xs[64 * 128];   // [row][kq swizzled] 16B slots
    __shared__ __align__(16) ushort Wl[128 * 64];   // [kc][ct][lane][j]
    const int t = threadIdx.x;

    // fold cursor zeroing into the gemm launch
    {
        int zi = blockIdx.x * 256 + t;
        if (zi < zero_n) zero_ptr[zi] = 0;
    }

    // stage W: coalesced read, scattered bf16 LDS write
    #pragma unroll
    for (int q = 0; q < 8; q++) {
        float4 wv = ((const float4*)W)[t * 8 + q];
        #pragma unroll
        for (int e = 0; e < 4; e++) {
            int L = t * 32 + q * 4 + e;
            int k = L >> 6, col = L & 63;
            int kc = k >> 5, kg = (k >> 3) & 3, j = k & 7;
            int ct = col >> 4, c16 = col & 15;
            float v = (e == 0) ? wv.x : (e == 1) ? wv.y : (e == 2) ? wv.z : wv.w;
            Wl[(((kc * 4 + ct) * 4 + kg) * 16 + c16) * 8 + j] = f2bf(v);
        }
    }
    // stage x: thread handles row t>>2, k-range (t&3)*32..+31 (coalesced)
    const int row0 = blockIdx.x * 64;
    {
        int row_l = t >> 2;
        int grow = row0 + row_l;
        #pragma unroll
        for (int qq = 0; qq < 4; qq++) {
            int kq = (t & 3) * 4 + qq;           // 16B slot index along k
            float4 v0 = make_float4(0.f, 0.f, 0.f, 0.f);
            float4 v1 = v0;
            if (grow < N) {
                const float4* xp = (const float4*)(x + (size_t)grow * IN_C + kq * 8);
                v0 = xp[0]; v1 = xp[1];
            }
            uint4 pk;
            pk.x = (uint)f2bf(v0.x) | ((uint)f2bf(v0.y) << 16);
            pk.y = (uint)f2bf(v0.z) | ((uint)f2bf(v0.w) << 16);
            pk.z = (uint)f2bf(v1.x) | ((uint)f2bf(v1.y) << 16);
            pk.w = (uint)f2bf(v1.z) | ((uint)f2bf(v1.w) << 16);
            int slot = row_l * 16 + (kq ^ (row_l & 7));
            *(uint4*)&xs[slot * 8] = pk;
        }
    }
    __syncthreads();

    const int wv_ = t >> 6;       // wave id: rows wv_*16..+15
    const int l = t & 63;
    const int c16 = l & 15;
    const int quad = l >> 4;
    const int row_a = wv_ * 16 + c16;     // A-row this lane loads

    f32x4 acc[4] = {{0.f, 0.f, 0.f, 0.f}, {0.f, 0.f, 0.f, 0.f},
                    {0.f, 0.f, 0.f, 0.f}, {0.f, 0.f, 0.f, 0.f}};

    #pragma unroll
    for (int kc = 0; kc < 4; kc++) {
        int kq = kc * 4 + quad;
        bf16x8 a = *(const bf16x8*)&xs[(row_a * 16 + (kq ^ (row_a & 7))) * 8];
        #pragma unroll
        for (int ct = 0; ct < 4; ct++) {
            bf16x8 b = *(const bf16x8*)&Wl[(((kc * 4 + ct) * 4 + quad) * 16 + c16) * 8];
            acc[ct] = __builtin_amdgcn_mfma_f32_16x16x32_bf16(a, b, acc[ct], 0, 0, 0);
        }
    }

    // epilogue: C/D layout col = ct*16 + c16, row = wv_*16 + quad*4 + reg
    float as4[4], ad4[4];
    #pragma unroll
    for (int ct = 0; ct < 4; ct++) {
        as4[ct] = a_src[ct * 16 + c16];
        ad4[ct] = a_dst[ct * 16 + c16];
    }
    #pragma unroll
    for (int reg = 0; reg < 4; reg++) {
        int row = row0 + wv_ * 16 + quad * 4 + reg;
        float ps = acc[0][reg] * as4[0] + acc[1][reg] * as4[1]
                 + acc[2][reg] * as4[2] + acc[3][reg] * as4[3];
        float pd = acc[0][reg] * ad4[0] + acc[1][reg] * ad4[1]
                 + acc[2][reg] * ad4[2] + acc[3][reg] * ad4[3];
        ps += __shfl_xor(ps, 1);  pd += __shfl_xor(pd, 1);
        ps += __shfl_xor(ps, 2);  pd += __shfl_xor(pd, 2);
        ps += __shfl_xor(ps, 4);  pd += __shfl_xor(pd, 4);
        ps += __shfl_xor(ps, 8);  pd += __shfl_xor(pd, 8);
        if (row < N) {
            #pragma unroll
            for (int ct = 0; ct < 4; ct++)
                h16[(size_t)row * OUT_C + ct * 16 + c16] = f2bf(acc[ct][reg]);
            if (c16 == 0) { s_src[row] = ps; s_dst[row] = pd; }
        }
    }
}

// Binning: 1024 threads, 4 edges/thread. Pass 1 histograms + stages packed
// records in LDS; reservation = <=2 independent global atomics/thread;
// pass 2 scatters from LDS with LDS fetch-add (no global reads).
__global__ __launch_bounds__(1024) void bin3_kernel(
    const int* __restrict__ src, const int* __restrict__ dst,
    int* __restrict__ ccur, int* __restrict__ ebufB, int E)
{
    __shared__ int    hist[NFBA];    // per-block bucket counts -> base cursors
    __shared__ int    bcur[NFBA];    // reserved global base -> running cursor
    __shared__ int    rbuf[CHUNK];   // packed records
    __shared__ ushort rfb[CHUNK];    // bucket id per record
    const int t = threadIdx.x;
    const int e0 = blockIdx.x * CHUNK;
    int tot = E - e0; if (tot > CHUNK) tot = CHUNK;

    for (int i = t; i < NFBA; i += BINT) hist[i] = 0;
    __syncthreads();

    // pass 1: vectorized read, LDS hist + stage packed record
    const int i0 = t * 4;
    if (i0 < tot) {
        if (i0 + 3 < tot) {
            int4 d4 = *(const int4*)(dst + e0 + i0);
            int4 s4 = *(const int4*)(src + e0 + i0);
            int dd_[4] = {d4.x, d4.y, d4.z, d4.w};
            int ss_[4] = {s4.x, s4.y, s4.z, s4.w};
            #pragma unroll
            for (int k = 0; k < 4; k++) {
                int fb = dd_[k] >> FSH;
                atomicAdd(&hist[fb], 1);
                rbuf[i0 + k] = ((dd_[k] & (FN - 1)) << PACKS) | ss_[k];
                rfb[i0 + k] = (ushort)fb;
            }
        } else {
            for (int k = 0; k < 4 && i0 + k < tot; k++) {
                int dd = dst[e0 + i0 + k], ss = src[e0 + i0 + k];
                int fb = dd >> FSH;
                atomicAdd(&hist[fb], 1);
                rbuf[i0 + k] = ((dd & (FN - 1)) << PACKS) | ss;
                rfb[i0 + k] = (ushort)fb;
            }
        }
    }
    __syncthreads();

    // reservation: one independent global atomic per touched bucket
    for (int fb = t; fb < NFBA; fb += BINT) {
        int v = hist[fb];
        bcur[fb] = (v > 0) ? atomicAdd(&ccur[fb * CSTR], v) : 0;
    }
    __syncthreads();

    // pass 2: LDS-only re-read, scatter via LDS fetch-add
    if (i0 < tot) {
        #pragma unroll
        for (int k = 0; k < 4; k++) {
            if (i0 + k < tot) {
                int fb = rfb[i0 + k];
                int pos = atomicAdd(&bcur[fb], 1);
                if (pos < CAPB)
                    ebufB[(size_t)fb * CAPB + pos] = rbuf[i0 + k];
            }
        }
    }
}

// One block per fine bucket (64 dst nodes), 512 threads = 8 waves: local
// hist/scan/scatter -> per-node CSR in LDS (packed int2), then 8 waves
// process nodes (nl += 8); lane = 2 bf16 channels, half-waves split edges,
// x4 unrolled gather. Per-node FP summation order unchanged vs 4-wave form.
__global__ __launch_bounds__(NBT) void nodeB_kernel(
    const int* __restrict__ ccurB, const int* __restrict__ ebufB,
    const float* __restrict__ s_src, const float* __restrict__ s_dst,
    const ushort* __restrict__ h16, const float* __restrict__ bias,
    float* __restrict__ out, int N)
{
    __shared__ __align__(8) int2 csr[CAPB];   // .x = src node, .y = exp bits
    __shared__ int lhist[FN], lofs[FN + 1], lcur[FN];

    const int b = blockIdx.x;
    const int t = threadIdx.x;
    const int node0 = b << FSH;
    const int nn = min(FN, N - node0);
    int cnt = ccurB[b * CSTR]; if (cnt > CAPB) cnt = CAPB;
    const int base = b * CAPB;

    if (t < FN) lhist[t] = 0;
    __syncthreads();
    for (int i = t; i < cnt; i += NBT)
        atomicAdd(&lhist[(ebufB[base + i] >> PACKS) & (FN - 1)], 1);
    __syncthreads();
    if (t < FN) {
        int v = lhist[t];
        int incl = v;
        #pragma unroll
        for (int off = 1; off < FN; off <<= 1) {
            int u = __shfl_up(incl, off);
            if (t >= off) incl += u;
        }
        lofs[t + 1] = incl;
        lcur[t] = incl - v;
        if (t == 0) lofs[0] = 0;
    }
    __syncthreads();
    for (int i = t; i < cnt; i += NBT) {      // re-read ebufB: L2-hit
        int pk = ebufB[base + i];
        int ld = (pk >> PACKS) & (FN - 1);
        int sj = pk & ((1 << PACKS) - 1);
        int q = atomicAdd(&lcur[ld], 1);
        float lg = s_src[sj] + s_dst[node0 + ld];
        lg = (lg > 0.f) ? lg : NEG_SLOPE * lg;
        csr[q] = make_int2(sj, __float_as_int(__expf(lg)));
    }
    __syncthreads();

    const int w = t >> 6;         // wave id 0..7
    const int l = t & 63;
    const int h2 = l >> 5;        // which edge of the half-wave pair
    const int lp = l & 31;        // channel pair index
    const float b0 = bias[2 * lp], b1 = bias[2 * lp + 1];

    for (int nl = w; nl < nn; nl += 8) {
        const int node = node0 + nl;
        const int jb = lofs[nl], je = lofs[nl + 1];
        float acc0 = 0.f, acc1 = 0.f, ds = 0.f;
        int j = jb + h2;
        for (; j + 6 < je; j += 8) {          // 4 edges per half-wave in flight
            int2 c0 = csr[j],     c1 = csr[j + 2];
            int2 c2 = csr[j + 4], c3 = csr[j + 6];
            float e0 = __int_as_float(c0.y), e1 = __int_as_float(c1.y);
            float e2 = __int_as_float(c2.y), e3 = __int_as_float(c3.y);
            uint u0 = *(const uint*)&h16[(size_t)c0.x * OUT_C + 2 * lp];
            uint u1 = *(const uint*)&h16[(size_t)c1.x * OUT_C + 2 * lp];
            uint u2 = *(const uint*)&h16[(size_t)c2.x * OUT_C + 2 * lp];
            uint u3 = *(const uint*)&h16[(size_t)c3.x * OUT_C + 2 * lp];
            ds += (e0 + e1) + (e2 + e3);
            acc0 += e0 * __uint_as_float(u0 << 16) + e1 * __uint_as_float(u1 << 16)
                  + e2 * __uint_as_float(u2 << 16) + e3 * __uint_as_float(u3 << 16);
            acc1 += e0 * __uint_as_float(u0 & 0xffff0000u) + e1 * __uint_as_float(u1 & 0xffff0000u)
                  + e2 * __uint_as_float(u2 & 0xffff0000u) + e3 * __uint_as_float(u3 & 0xffff0000u);
        }
        for (; j < je; j += 2) {
            int2 c = csr[j];
            float e = __int_as_float(c.y);
            uint u = *(const uint*)&h16[(size_t)c.x * OUT_C + 2 * lp];
            ds += e;
            acc0 += e * __uint_as_float(u << 16);
            acc1 += e * __uint_as_float(u & 0xffff0000u);
        }
        acc0 += __shfl_xor(acc0, 32);
        acc1 += __shfl_xor(acc1, 32);
        ds   += __shfl_xor(ds, 32);

        float ls = s_src[node] + s_dst[node];
        ls = (ls > 0.f) ? ls : NEG_SLOPE * ls;
        float es = __expf(ls);
        uint us = *(const uint*)&h16[(size_t)node * OUT_C + 2 * lp];
        acc0 += es * __uint_as_float(us << 16);
        acc1 += es * __uint_as_float(us & 0xffff0000u);
        ds += es;

        float inv = 1.f / (ds + GAT_EPS);
        float v0 = acc0 * inv + b0;
        float v1 = acc1 * inv + b1;
        v0 = (v0 > 0.f) ? v0 : (__expf(v0) - 1.f);
        v1 = (v1 > 0.f) ? v1 : (__expf(v1) - 1.f);
        if (l < 32) *(float2*)&out[(size_t)node * OUT_C + 2 * lp] = make_float2(v0, v1);
    }
}

extern "C" void kernel_launch(void* const* d_in, const int* in_sizes, int n_in,
                              void* d_out, int out_size, void* d_ws, size_t ws_size,
                              hipStream_t stream)
{
    const float* x     = (const float*)d_in[0];
    const int*   ei    = (const int*)d_in[1];
    const float* W     = (const float*)d_in[2];
    const float* a_src = (const float*)d_in[3];
    const float* a_dst = (const float*)d_in[4];
    const float* b     = (const float*)d_in[5];
    float* out = (float*)d_out;

    const int N = in_sizes[0] / IN_C;
    const int E = in_sizes[1] / 2;
    const int NFB = (N + FN - 1) >> FSH;           // fine buckets (1563)
    const int GB = (N + 63) / 64;
    const int GBIN = (E + CHUNK - 1) / CHUNK;
    const int* src = ei;
    const int* dst = ei + E;

    // ws: h16[N*64] us | s_src[N] f | s_dst[N] f | ccur[NFBA*CSTR] | ebufB[NFBA*CAPB]
    ushort* h16    = (ushort*)d_ws;
    float* s_src_p = (float*)(h16 + (size_t)N * OUT_C);
    float* s_dst_p = s_src_p + N;
    int*   ccur    = (int*)(s_dst_p + N);
    int*   ebufB   = ccur + NFBA * CSTR;

    gemm_kernel<<<GB, 256, 0, stream>>>(x, W, a_src, a_dst, h16, s_src_p, s_dst_p,
                                        N, ccur, NFBA * CSTR);
    bin3_kernel<<<GBIN, BINT, 0, stream>>>(src, dst, ccur, ebufB, E);
    nodeB_kernel<<<NFB, NBT, 0, stream>>>(ccur, ebufB, s_src_p, s_dst_p, h16, b, out, N);
}